// Round 1
// baseline (116.479 us; speedup 1.0000x reference)
//
#include <hip/hip_runtime.h>
#include <hip/hip_bf16.h>
#include <math.h>

typedef float floatx16 __attribute__((ext_vector_type(16)));
typedef __bf16 bf16x8 __attribute__((ext_vector_type(8)));

#define SEQ 2048
#define NH 8
#define DH 64
#define HEADS 16
#define RS (NH * DH)   // 512 floats between consecutive sequence positions

__device__ __forceinline__ unsigned int pk2bf(float a, float b) {
  union { __hip_bfloat162 h2; unsigned int u; } c;
  c.h2 = __float22bfloat162_rn(make_float2(a, b));
  return c.u;
}

// v_permlane32_swap_b32, orientation probed at runtime (R12-verified).
__device__ __forceinline__ void hswap_fwd(unsigned& a, unsigned& b) {
  asm volatile("v_permlane32_swap_b32 %0, %1" : "+v"(a), "+v"(b));
}
__device__ __forceinline__ void hswap_rev(unsigned& a, unsigned& b) {
  asm volatile("v_permlane32_swap_b32 %0, %1" : "+v"(b), "+v"(a));
}

// ---- fully fused attention: NO workspace, NO pack kernel.
//      K fragments: same addressing pattern as Q fragments (32 rows x 2 float4,
//      coalesced, 64B-line-complete across hl), converted bf16 in-register.
//      V fragments: 8 strided dword loads per fragment (contraction dim s must
//      sit in registers; each instr reads two fully-used 128B segments, L2-hit
//      via the bx&15 XCD affinity: 2 heads x 2MB fp32 KV = 4MB per XCD L2).
//      Everything else (32x32 MFMA, fixed-shift softmax, permlane P-transform,
//      4-phase LDS merge) identical to the 100us baseline.
#define SMEM_BYTES 37376   // oM [8][16][72]*4 = 36864 + lM [8][16]*4 = 512

__global__ __launch_bounds__(512)
void attn(const float* __restrict__ q, const float* __restrict__ k,
          const float* __restrict__ v, float* __restrict__ out) {
  __shared__ __align__(16) char smem[SMEM_BYTES];
  float* oM = (float*)smem;                             // [8][16][72]
  float* lM = (float*)(smem + 8 * 16 * 72 * 4);         // [8][16]

  const int tid  = threadIdx.x;
  const int wave = tid >> 6;
  const int lane = tid & 63;
  const int l32  = lane & 31;
  const int hl   = lane >> 5;
  const int wq   = wave >> 2;        // q-half (0/1)
  const int wk   = wave & 3;         // key-quarter (0..3)

  // probe permlane32_swap orientation (wave-uniform)
  unsigned px = (unsigned)lane, py = (unsigned)lane + 100u;
  hswap_fwd(px, py);
  const bool mir = (__builtin_amdgcn_readfirstlane(px) != 0u);

  const int bx   = blockIdx.x;
  const int head = bx & 15;          // XCD h%8 affinity (16 blocks/head share L2)
  const int qh2  = bx >> 4;          // 0..15, 128 q-rows per block
  const int n = head >> 3, h = head & 7;

  const float* kf = k + ((size_t)n * SEQ * NH + h) * DH;
  const float* vf = v + ((size_t)n * SEQ * NH + h) * DH;

  // Q B-fragments: lane holds Q[q = qh2*128 + wq*64 + qs*32 + l32][d = kk*16 + hl*8 + j]
  bf16x8 qB[2][4];
  #pragma unroll
  for (int qs = 0; qs < 2; ++qs)
    #pragma unroll
    for (int kk = 0; kk < 4; ++kk) {
      const int row = qh2 * 128 + wq * 64 + qs * 32 + l32;
      const float* src = q + ((size_t)((n * SEQ + row) * NH + h)) * DH + kk * 16 + hl * 8;
      float4 x0 = *(const float4*)src;
      float4 x1 = *(const float4*)(src + 4);
      union { unsigned int u32[4]; bf16x8 v8; } u;
      u.u32[0] = pk2bf(x0.x, x0.y); u.u32[1] = pk2bf(x0.z, x0.w);
      u.u32[2] = pk2bf(x1.x, x1.y); u.u32[3] = pk2bf(x1.z, x1.w);
      qB[qs][kk] = u.v8;
    }

  floatx16 o[2][2];
  float lsum[2];
  #pragma unroll
  for (int qs = 0; qs < 2; ++qs) {
    lsum[qs] = 0.f;
    #pragma unroll
    for (int d = 0; d < 2; ++d)
      #pragma unroll
      for (int i = 0; i < 16; ++i) o[qs][d][i] = 0.f;
  }

  const float S = 0.125f * 1.4426950408889634f;
  const float C = 12.0f;

  for (int it = 0; it < 8; ++it) {
    const int kt = wk * 8 + it;      // this wave's key-quarter, 512 keys
    const float* kt_base = kf + (size_t)kt * 64 * RS;
    const float* vt_base = vf + (size_t)kt * 64 * RS;

    // ALL fragment loads at iter top (direct fp32 -> bf16 in-register)
    // K: lane holds K[row = kt*64 + ks2*32 + l32][d = kk*16 + hl*8 + j]
    bf16x8 kA[2][4];
    #pragma unroll
    for (int ks2 = 0; ks2 < 2; ++ks2)
      #pragma unroll
      for (int kk = 0; kk < 4; ++kk) {
        const float* src = kt_base + (size_t)(ks2 * 32 + l32) * RS + kk * 16 + hl * 8;
        float4 x0 = *(const float4*)src;
        float4 x1 = *(const float4*)(src + 4);
        union { unsigned int u32[4]; bf16x8 v8; } u;
        u.u32[0] = pk2bf(x0.x, x0.y); u.u32[1] = pk2bf(x0.z, x0.w);
        u.u32[2] = pk2bf(x1.x, x1.y); u.u32[3] = pk2bf(x1.z, x1.w);
        kA[ks2][kk] = u.v8;
      }
    // V: lane holds V[s = kt*64 + ss*16 + hl*8 + j][d = dsub*32 + l32]
    bf16x8 vB[4][2];   // [ss][dsub]
    #pragma unroll
    for (int ss = 0; ss < 4; ++ss)
      #pragma unroll
      for (int dsub = 0; dsub < 2; ++dsub) {
        const float* src = vt_base + (size_t)(ss * 16 + hl * 8) * RS + dsub * 32 + l32;
        float w0 = src[0 * RS], w1 = src[1 * RS], w2 = src[2 * RS], w3 = src[3 * RS];
        float w4 = src[4 * RS], w5 = src[5 * RS], w6 = src[6 * RS], w7 = src[7 * RS];
        union { unsigned int u32[4]; bf16x8 v8; } u;
        u.u32[0] = pk2bf(w0, w1); u.u32[1] = pk2bf(w2, w3);
        u.u32[2] = pk2bf(w4, w5); u.u32[3] = pk2bf(w6, w7);
        vB[ss][dsub] = u.v8;
      }

    #pragma unroll
    for (int ks2 = 0; ks2 < 2; ++ks2) {
      floatx16 acc2[2];
      #pragma unroll
      for (int i = 0; i < 16; ++i) acc2[0][i] = 0.f;
      #pragma unroll
      for (int kk = 0; kk < 4; ++kk)
        acc2[0] = __builtin_amdgcn_mfma_f32_32x32x16_bf16(kA[ks2][kk], qB[0][kk], acc2[0], 0, 0, 0);

      #pragma unroll
      for (int m = 0; m < 2; ++m) {
        unsigned pk[8];
        #pragma unroll
        for (int g2 = 0; g2 < 4; ++g2) {
          float p0 = __builtin_amdgcn_exp2f(acc2[m][4 * g2 + 0] * S - C);
          float p1 = __builtin_amdgcn_exp2f(acc2[m][4 * g2 + 1] * S - C);
          float p2 = __builtin_amdgcn_exp2f(acc2[m][4 * g2 + 2] * S - C);
          float p3 = __builtin_amdgcn_exp2f(acc2[m][4 * g2 + 3] * S - C);
          lsum[m] += (p0 + p1) + (p2 + p3);
          pk[g2 * 2]     = pk2bf(p0, p1);
          pk[g2 * 2 + 1] = pk2bf(p2, p3);
        }

        if (m == 0) {
          #pragma unroll
          for (int i = 0; i < 16; ++i) acc2[1][i] = 0.f;
          #pragma unroll
          for (int kk = 0; kk < 4; ++kk)
            acc2[1] = __builtin_amdgcn_mfma_f32_32x32x16_bf16(kA[ks2][kk], qB[1][kk], acc2[1], 0, 0, 0);
        }

        union { unsigned u32[4]; bf16x8 v8; } A1, A2;
        A1.u32[0] = pk[0]; A1.u32[2] = pk[2];
        A1.u32[1] = pk[1]; A1.u32[3] = pk[3];
        A2.u32[0] = pk[4]; A2.u32[2] = pk[6];
        A2.u32[1] = pk[5]; A2.u32[3] = pk[7];
        if (!mir) {
          hswap_fwd(A1.u32[0], A1.u32[2]); hswap_fwd(A1.u32[1], A1.u32[3]);
          hswap_fwd(A2.u32[0], A2.u32[2]); hswap_fwd(A2.u32[1], A2.u32[3]);
        } else {
          hswap_rev(A1.u32[0], A1.u32[2]); hswap_rev(A1.u32[1], A1.u32[3]);
          hswap_rev(A2.u32[0], A2.u32[2]); hswap_rev(A2.u32[1], A2.u32[3]);
        }

        o[m][0] = __builtin_amdgcn_mfma_f32_32x32x16_bf16(A1.v8, vB[ks2 * 2][0],     o[m][0], 0, 0, 0);
        o[m][1] = __builtin_amdgcn_mfma_f32_32x32x16_bf16(A1.v8, vB[ks2 * 2][1],     o[m][1], 0, 0, 0);
        o[m][0] = __builtin_amdgcn_mfma_f32_32x32x16_bf16(A2.v8, vB[ks2 * 2 + 1][0], o[m][0], 0, 0, 0);
        o[m][1] = __builtin_amdgcn_mfma_f32_32x32x16_bf16(A2.v8, vB[ks2 * 2 + 1][1], o[m][1], 0, 0, 0);
      }
    }
  }

  // lsum: lanes L and L+32 hold disjoint key subsets of the same q
  #pragma unroll
  for (int qs = 0; qs < 2; ++qs)
    lsum[qs] += __shfl_xor(lsum[qs], 32, 64);

  // ---- 4-phase merge: sum the 4 key-quarter waves of each q-half ----
  const int r32  = tid >> 4;          // 0..31 row-slot
  const int wqr  = r32 >> 4;          // which q-half this thread merges
  const int prow = r32 & 15;          // row within phase group
  const int col4 = tid & 15;          // float4 column
  #pragma unroll
  for (int p = 0; p < 4; ++p) {
    const int qsub = p >> 1, rh = p & 1;
    __syncthreads();
    #pragma unroll
    for (int r8 = 0; r8 < 8; ++r8) {
      const int r   = rh * 8 + r8;
      const int rip = (r8 & 3) + 4 * hl + 8 * (r8 >> 2);   // row in phase, 0..15
      oM[(wave * 16 + rip) * 72 + l32]      = o[qsub][0][r];
      oM[(wave * 16 + rip) * 72 + 32 + l32] = o[qsub][1][r];
    }
    if (lane < 32 && ((lane >> 4) & 1) == rh) lM[wave * 16 + (lane & 15)] = lsum[qsub];
    __syncthreads();
    float4 s = make_float4(0.f, 0.f, 0.f, 0.f);
    float l = 0.f;
    #pragma unroll
    for (int j = 0; j < 4; ++j) {
      const int w = wqr * 4 + j;
      float4 t4 = *(const float4*)&oM[(w * 16 + prow) * 72 + col4 * 4];
      s.x += t4.x; s.y += t4.y; s.z += t4.z; s.w += t4.w;
      l += lM[w * 16 + prow];
    }
    float inv = 1.f / l;
    const int grow = qh2 * 128 + wqr * 64 + p * 16 + prow;
    float4 st; st.x = s.x * inv; st.y = s.y * inv; st.z = s.z * inv; st.w = s.w * inv;
    *(float4*)(out + ((size_t)((n * SEQ + grow) * NH + h)) * DH + col4 * 4) = st;
  }
}

extern "C" void kernel_launch(void* const* d_in, const int* in_sizes, int n_in,
                              void* d_out, int out_size, void* d_ws, size_t ws_size,
                              hipStream_t stream) {
  const float* q = (const float*)d_in[0];
  const float* k = (const float*)d_in[1];
  const float* v = (const float*)d_in[2];
  float* out = (float*)d_out;
  (void)in_sizes; (void)n_in; (void)out_size; (void)d_ws; (void)ws_size;

  attn<<<HEADS * (SEQ / 128), 512, 0, stream>>>(q, k, v, out);
}